// Round 4
// baseline (1541.950 us; speedup 1.0000x reference)
//
#include <hip/hip_runtime.h>

#define F_IN 512
#define HDIM 64
#define RSHIFT 7
#define RWIDTH 128
#define MAXNB 1024
#define CHUNK 4096

typedef _Float16 f16;
typedef _Float16 f16x8 __attribute__((ext_vector_type(8)));
typedef float f32x4 __attribute__((ext_vector_type(4)));

// wsum[k] = sum_j linW[j][k]; wsum[64] = sum_j linB[j]
__global__ void prep_kernel(const float* __restrict__ linW,
                            const float* __restrict__ linB,
                            float* __restrict__ wsum) {
    int k = threadIdx.x;
    float s = 0.f;
    for (int j = 0; j < HDIM; ++j) s += linW[j * HDIM + k];
    wsum[k] = s;
    if (k == 0) {
        float b = 0.f;
        for (int j = 0; j < HDIM; ++j) b += linB[j];
        wsum[HDIM] = b;
    }
}

// fc_weight as f16 in B-fragment order:
// wf[((s*4 + c)*64 + lane)*8 + j] = W[c*16 + (lane&15)][s*32 + (lane>>4)*8 + j]
__global__ __launch_bounds__(256) void prep_w16_kernel(const float* __restrict__ W,
                                                       f16* __restrict__ wf) {
    int t = blockIdx.x * 256 + threadIdx.x;   // 0..4095
    int s = t >> 8;
    int c = (t >> 6) & 3;
    int l = t & 63;
    int row = c * 16 + (l & 15);
    int kb = s * 32 + ((l >> 4) << 3);
#pragma unroll
    for (int j = 0; j < 8; ++j)
        wf[(size_t)t * 8 + j] = (f16)W[row * F_IN + kb + j];
}

__global__ void zero_int_kernel(int* __restrict__ p, int n) {
    int i = blockIdx.x * blockDim.x + threadIdx.x;
    if (i < n) p[i] = 0;
}

// bucket histogram, LDS-pre-aggregated
__global__ __launch_bounds__(256) void bhist_kernel(const int* __restrict__ row,
                                                    int* __restrict__ bh,
                                                    int n_edges, int NB) {
    __shared__ int lh[MAXNB];
    for (int i = threadIdx.x; i < NB; i += 256) lh[i] = 0;
    __syncthreads();
    for (int e = blockIdx.x * 256 + threadIdx.x; e < n_edges; e += gridDim.x * 256)
        atomicAdd(&lh[row[e] >> RSHIFT], 1);
    __syncthreads();
    for (int i = threadIdx.x; i < NB; i += 256)
        if (lh[i]) atomicAdd(&bh[i], lh[i]);
}

// one block, 1024 threads: exclusive scan of bh -> boff; init gcur
__global__ __launch_bounds__(1024) void bscan_kernel(const int* __restrict__ bh,
                                                     int* __restrict__ boff,
                                                     int* __restrict__ gcur,
                                                     int NB, int n_edges) {
    __shared__ int s[1024];
    const int t = threadIdx.x;
    int v = (t < NB) ? bh[t] : 0;
    s[t] = v;
    __syncthreads();
#pragma unroll
    for (int off = 1; off < 1024; off <<= 1) {
        int x = (t >= off) ? s[t - off] : 0;
        __syncthreads();
        s[t] += x;
        __syncthreads();
    }
    if (t < NB) {
        int o = s[t] - v;
        boff[t] = o;
        gcur[t] = o;
    }
    if (t == NB) boff[NB] = n_edges;
}

// partition: per-block counting sort by bucket in LDS, append runs to global regions
__global__ __launch_bounds__(256) void part_kernel(const int* __restrict__ row,
                                                   const int* __restrict__ col,
                                                   const float* __restrict__ w,
                                                   int* __restrict__ gcur,
                                                   int2* __restrict__ ebin,
                                                   int n_edges, int NB) {
    __shared__ int2 stg[CHUNK];             // 32 KB
    __shared__ unsigned short sbin[CHUNK];  // 8 KB
    __shared__ int lh[MAXNB];               // counts -> then (gbase - lstart)
    __shared__ int lofs[MAXNB];             // running local cursors
    __shared__ int psum[256];
    const int t = threadIdx.x;
    const int base = blockIdx.x * CHUNK;
    const int cnt = min(CHUNK, n_edges - base);

    for (int i = t; i < NB; i += 256) lh[i] = 0;
    __syncthreads();
    for (int i = t; i < cnt; i += 256)
        atomicAdd(&lh[row[base + i] >> RSHIFT], 1);
    __syncthreads();
    // exclusive scan of lh (4 bins per thread, contiguous)
    int loc[4];
    int s0 = 0;
#pragma unroll
    for (int j = 0; j < 4; ++j) {
        int b = t * 4 + j;
        int c = (b < NB) ? lh[b] : 0;
        loc[j] = s0;
        s0 += c;
    }
    psum[t] = s0;
    __syncthreads();
#pragma unroll
    for (int off = 1; off < 256; off <<= 1) {
        int x = (t >= off) ? psum[t - off] : 0;
        __syncthreads();
        psum[t] += x;
        __syncthreads();
    }
    int pbase = psum[t] - s0;
#pragma unroll
    for (int j = 0; j < 4; ++j) {
        int b = t * 4 + j;
        if (b < NB) lofs[b] = pbase + loc[j];
    }
    __syncthreads();
    // scatter into LDS staging, bucket-sorted
    for (int i = t; i < cnt; i += 256) {
        int r = row[base + i];
        int b = r >> RSHIFT;
        int p = atomicAdd(&lofs[b], 1);
        stg[p] = make_int2(__float_as_int(w[base + i]),
                           (col[base + i] << RSHIFT) | (r & (RWIDTH - 1)));
        sbin[p] = (unsigned short)b;
    }
    __syncthreads();
    // reserve global space per bucket; store (gbase - lstart)
    for (int b = t; b < NB; b += 256) {
        int c = lh[b];
        if (c) {
            int lstart = lofs[b] - c;
            int gb = atomicAdd(&gcur[b], c);
            lh[b] = gb - lstart;
        }
    }
    __syncthreads();
    // write out (contiguous per-bucket runs)
    for (int p = t; p < cnt; p += 256) {
        int b = sbin[p];
        ebin[lh[b] + p] = stg[p];
    }
}

// H16[n][j] = (f16) sum_k X[n][k]*W[j][k]; LDS-free MFMA, 4 waves x 16 rows
__global__ __launch_bounds__(256) void gemm_mfma_kernel(const float* __restrict__ X,
                                                        const f16* __restrict__ wf,
                                                        f16* __restrict__ H,
                                                        int n_nodes) {
    const int lane = threadIdx.x & 63;
    const int w = threadIdx.x >> 6;
    const int m0 = blockIdx.x * 64 + w * 16;
    int arow = m0 + (lane & 15);
    if (arow >= n_nodes) arow = n_nodes - 1;
    const float* xp = X + (size_t)arow * F_IN + ((lane >> 4) << 3);
    const f16x8* wfv = reinterpret_cast<const f16x8*>(wf);

    f32x4 acc0 = {}, acc1 = {}, acc2 = {}, acc3 = {};
    for (int s = 0; s < 16; ++s) {
        const f16x8* bp = wfv + (size_t)(s * 4) * 64 + lane;
        f16x8 b0 = bp[0];
        f16x8 b1 = bp[64];
        f16x8 b2 = bp[128];
        f16x8 b3 = bp[192];
        float4 xa = *reinterpret_cast<const float4*>(xp + s * 32);
        float4 xb = *reinterpret_cast<const float4*>(xp + s * 32 + 4);
        f16x8 a;
        a[0] = (f16)xa.x; a[1] = (f16)xa.y; a[2] = (f16)xa.z; a[3] = (f16)xa.w;
        a[4] = (f16)xb.x; a[5] = (f16)xb.y; a[6] = (f16)xb.z; a[7] = (f16)xb.w;
        acc0 = __builtin_amdgcn_mfma_f32_16x16x32_f16(a, b0, acc0, 0, 0, 0);
        acc1 = __builtin_amdgcn_mfma_f32_16x16x32_f16(a, b1, acc1, 0, 0, 0);
        acc2 = __builtin_amdgcn_mfma_f32_16x16x32_f16(a, b2, acc2, 0, 0, 0);
        acc3 = __builtin_amdgcn_mfma_f32_16x16x32_f16(a, b3, acc3, 0, 0, 0);
    }

    const int colj = lane & 15;
#pragma unroll
    for (int j = 0; j < 4; ++j) {
        int r = m0 + ((lane >> 4) << 2) + j;
        if (r < n_nodes) {
            f16* hp = H + (size_t)r * HDIM + colj;
            hp[0]  = (f16)acc0[j];
            hp[16] = (f16)acc1[j];
            hp[32] = (f16)acc2[j];
            hp[48] = (f16)acc3[j];
        }
    }
}

// one block per bucket: LDS tile accumulate + fused bias/PReLU/wsum-dot -> z
__global__ __launch_bounds__(256) void agg_finalize_kernel(const int* __restrict__ boff,
                                                           const int2* __restrict__ ebin,
                                                           const f16* __restrict__ h,
                                                           const float* __restrict__ gbias,
                                                           const float* __restrict__ wsum,
                                                           const float* __restrict__ prelu_a,
                                                           float* __restrict__ z,
                                                           int n_nodes) {
    __shared__ float tile[RWIDTH][HDIM];    // 32 KB
    const int b = blockIdx.x;
    const int lane = threadIdx.x & 63;
    const int wv = threadIdx.x >> 6;
    for (int i = threadIdx.x; i < RWIDTH * HDIM; i += 256)
        (&tile[0][0])[i] = 0.f;
    __syncthreads();

    const int e0 = boff[b], e1 = boff[b + 1];
    const int tot = e1 - e0;
    const int per = (tot + 3) >> 2;
    int i = e0 + wv * per;
    const int e = min(i + per, e1);
    for (; i + 1 < e; i += 2) {
        int2 r0 = ebin[i];
        int2 r1 = ebin[i + 1];
        float h0 = (float)h[(size_t)(r0.y >> RSHIFT) * HDIM + lane];
        float h1 = (float)h[(size_t)(r1.y >> RSHIFT) * HDIM + lane];
        atomicAdd(&tile[r0.y & (RWIDTH - 1)][lane], __int_as_float(r0.x) * h0);
        atomicAdd(&tile[r1.y & (RWIDTH - 1)][lane], __int_as_float(r1.x) * h1);
    }
    if (i < e) {
        int2 r0 = ebin[i];
        float h0 = (float)h[(size_t)(r0.y >> RSHIFT) * HDIM + lane];
        atomicAdd(&tile[r0.y & (RWIDTH - 1)][lane], __int_as_float(r0.x) * h0);
    }
    __syncthreads();

    const float a = prelu_a[0];
    const float wl = wsum[lane];
    const float gb = gbias[lane];
    const float c0 = wsum[HDIM];
#pragma unroll 4
    for (int rr = 0; rr < RWIDTH / 4; ++rr) {
        int r = wv * (RWIDTH / 4) + rr;
        int gr = b * RWIDTH + r;
        if (gr >= n_nodes) break;
        float v = tile[r][lane] + gb;
        v = (v >= 0.f) ? v : a * v;
        float p = v * wl;
#pragma unroll
        for (int m = 32; m >= 1; m >>= 1) p += __shfl_xor(p, m, 64);
        if (lane == 0) z[gr] = p + c0;
    }
}

extern "C" void kernel_launch(void* const* d_in, const int* in_sizes, int n_in,
                              void* d_out, int out_size, void* d_ws, size_t ws_size,
                              hipStream_t stream) {
    const float* x1    = (const float*)d_in[0];
    const float* x2    = (const float*)d_in[1];
    const int*   erow  = (const int*)d_in[2];
    const int*   ecol  = (const int*)d_in[3];
    const float* ew    = (const float*)d_in[4];
    const float* fcw   = (const float*)d_in[5];
    const float* gbias = (const float*)d_in[6];
    const float* pa    = (const float*)d_in[7];
    const float* linw  = (const float*)d_in[8];
    const float* linb  = (const float*)d_in[9];
    float* out = (float*)d_out;

    const int n_nodes = in_sizes[0] / F_IN;   // 100000
    const int n_edges = in_sizes[2];          // 1600000
    const int NB = (n_nodes + RWIDTH - 1) >> RSHIFT;   // 782 (<= MAXNB)

    // workspace layout
    f16*   h16  = (f16*)d_ws;                           // n_nodes*64 f16
    f16*   wf   = h16 + (size_t)n_nodes * HDIM;         // 64*512 f16
    int2*  ebin = (int2*)(wf + 64 * F_IN);              // n_edges int2
    int*   bh   = (int*)(ebin + n_edges);               // MAXNB
    int*   boff = bh + MAXNB;                           // MAXNB+1
    int*   gcur = boff + MAXNB + 1;                     // MAXNB
    float* wsum = (float*)(gcur + MAXNB);               // 65 f32

    prep_kernel<<<1, 64, 0, stream>>>(linw, linb, wsum);
    prep_w16_kernel<<<16, 256, 0, stream>>>(fcw, wf);

    zero_int_kernel<<<(NB + 255) / 256, 256, 0, stream>>>(bh, NB);
    bhist_kernel<<<256, 256, 0, stream>>>(erow, bh, n_edges, NB);
    bscan_kernel<<<1, 1024, 0, stream>>>(bh, boff, gcur, NB, n_edges);
    part_kernel<<<(n_edges + CHUNK - 1) / CHUNK, 256, 0, stream>>>(erow, ecol, ew, gcur,
                                                                   ebin, n_edges, NB);

    const int gemm_grid = (n_nodes + 63) / 64;
    const float* xs[2] = {x1, x2};
    for (int s = 0; s < 2; ++s) {
        gemm_mfma_kernel<<<gemm_grid, 256, 0, stream>>>(xs[s], wf, h16, n_nodes);
        agg_finalize_kernel<<<NB, 256, 0, stream>>>(boff, ebin, h16, gbias, wsum, pa,
                                                    out + (size_t)s * n_nodes, n_nodes);
    }
}

// Round 5
// 298.776 us; speedup vs baseline: 5.1609x; 5.1609x over previous
//
#include <hip/hip_runtime.h>

#define F_IN 512
#define HDIM 64
#define RSHIFT 7
#define RWIDTH 128
#define MAXNB 1024
#define CHUNK 4096

typedef _Float16 f16;
typedef _Float16 f16x8 __attribute__((ext_vector_type(8)));
typedef float f32x4 __attribute__((ext_vector_type(4)));

// wsum[k] = sum_j linW[j][k]; wsum[64] = sum_j linB[j]
__global__ void prep_kernel(const float* __restrict__ linW,
                            const float* __restrict__ linB,
                            float* __restrict__ wsum) {
    int k = threadIdx.x;
    float s = 0.f;
    for (int j = 0; j < HDIM; ++j) s += linW[j * HDIM + k];
    wsum[k] = s;
    if (k == 0) {
        float b = 0.f;
        for (int j = 0; j < HDIM; ++j) b += linB[j];
        wsum[HDIM] = b;
    }
}

// fc_weight as f16 in B-fragment order:
// wf[((s*4 + c)*64 + lane)*8 + j] = W[c*16 + (lane&15)][s*32 + (lane>>4)*8 + j]
__global__ __launch_bounds__(256) void prep_w16_kernel(const float* __restrict__ W,
                                                       f16* __restrict__ wf) {
    int t = blockIdx.x * 256 + threadIdx.x;   // 0..4095
    int s = t >> 8;
    int c = (t >> 6) & 3;
    int l = t & 63;
    int row = c * 16 + (l & 15);
    int kb = s * 32 + ((l >> 4) << 3);
#pragma unroll
    for (int j = 0; j < 8; ++j)
        wf[(size_t)t * 8 + j] = (f16)W[row * F_IN + kb + j];
}

__global__ void zero_int_kernel(int* __restrict__ p, int n) {
    int i = blockIdx.x * blockDim.x + threadIdx.x;
    if (i < n) p[i] = 0;
}

// bucket histogram, LDS-pre-aggregated
__global__ __launch_bounds__(256) void bhist_kernel(const int* __restrict__ row,
                                                    int* __restrict__ bh,
                                                    int n_edges, int NB) {
    __shared__ int lh[MAXNB];
    for (int i = threadIdx.x; i < NB; i += 256) lh[i] = 0;
    __syncthreads();
    for (int e = blockIdx.x * 256 + threadIdx.x; e < n_edges; e += gridDim.x * 256)
        atomicAdd(&lh[row[e] >> RSHIFT], 1);
    __syncthreads();
    for (int i = threadIdx.x; i < NB; i += 256)
        if (lh[i]) atomicAdd(&bh[i], lh[i]);
}

// one block: exclusive scan of bh -> boff; init gcur; ptr[n_nodes] = n_edges
__global__ __launch_bounds__(1024) void bscan_kernel(const int* __restrict__ bh,
                                                     int* __restrict__ boff,
                                                     int* __restrict__ gcur,
                                                     int* __restrict__ ptr,
                                                     int NB, int n_nodes, int n_edges) {
    __shared__ int s[1024];
    const int t = threadIdx.x;
    int v = (t < NB) ? bh[t] : 0;
    s[t] = v;
    __syncthreads();
#pragma unroll
    for (int off = 1; off < 1024; off <<= 1) {
        int x = (t >= off) ? s[t - off] : 0;
        __syncthreads();
        s[t] += x;
        __syncthreads();
    }
    if (t < NB) {
        int o = s[t] - v;
        boff[t] = o;
        gcur[t] = o;
    }
    if (t == NB) boff[NB] = n_edges;
    if (t == 0) ptr[n_nodes] = n_edges;
}

// partition: per-block counting sort by bucket in LDS, append runs to global regions.
// record: (w_bits, col<<7 | row&127)
__global__ __launch_bounds__(256) void part_kernel(const int* __restrict__ row,
                                                   const int* __restrict__ col,
                                                   const float* __restrict__ w,
                                                   int* __restrict__ gcur,
                                                   int2* __restrict__ etmp,
                                                   int n_edges, int NB) {
    __shared__ int2 stg[CHUNK];             // 32 KB
    __shared__ unsigned short sbin[CHUNK];  // 8 KB
    __shared__ int lh[MAXNB];
    __shared__ int lofs[MAXNB];
    __shared__ int psum[256];
    const int t = threadIdx.x;
    const int base = blockIdx.x * CHUNK;
    const int cnt = min(CHUNK, n_edges - base);

    for (int i = t; i < NB; i += 256) lh[i] = 0;
    __syncthreads();
    for (int i = t; i < cnt; i += 256)
        atomicAdd(&lh[row[base + i] >> RSHIFT], 1);
    __syncthreads();
    int loc[4];
    int s0 = 0;
#pragma unroll
    for (int j = 0; j < 4; ++j) {
        int b = t * 4 + j;
        int c = (b < NB) ? lh[b] : 0;
        loc[j] = s0;
        s0 += c;
    }
    psum[t] = s0;
    __syncthreads();
#pragma unroll
    for (int off = 1; off < 256; off <<= 1) {
        int x = (t >= off) ? psum[t - off] : 0;
        __syncthreads();
        psum[t] += x;
        __syncthreads();
    }
    int pbase = psum[t] - s0;
#pragma unroll
    for (int j = 0; j < 4; ++j) {
        int b = t * 4 + j;
        if (b < NB) lofs[b] = pbase + loc[j];
    }
    __syncthreads();
    for (int i = t; i < cnt; i += 256) {
        int r = row[base + i];
        int b = r >> RSHIFT;
        int p = atomicAdd(&lofs[b], 1);
        stg[p] = make_int2(__float_as_int(w[base + i]),
                           (col[base + i] << RSHIFT) | (r & (RWIDTH - 1)));
        sbin[p] = (unsigned short)b;
    }
    __syncthreads();
    for (int b = t; b < NB; b += 256) {
        int c = lh[b];
        if (c) {
            int lstart = lofs[b] - c;
            int gb = atomicAdd(&gcur[b], c);
            lh[b] = gb - lstart;
        }
    }
    __syncthreads();
    for (int p = t; p < cnt; p += 256) {
        int b = sbin[p];
        etmp[lh[b] + p] = stg[p];
    }
}

// per-bucket counting sort -> full CSR order; write ptr. record out: (w_bits, col)
__global__ __launch_bounds__(256) void bsort_kernel(const int* __restrict__ boff,
                                                    const int2* __restrict__ etmp,
                                                    int2* __restrict__ ebin,
                                                    int* __restrict__ ptr,
                                                    int n_nodes) {
    __shared__ int nh[RWIDTH], lo[RWIDTH], lc[RWIDTH];
    const int b = blockIdx.x;
    const int t = threadIdx.x;
    const int e0 = boff[b], e1 = boff[b + 1];
    const int cnt = e1 - e0;
    if (t < RWIDTH) nh[t] = 0;
    __syncthreads();
    for (int i = t; i < cnt; i += 256)
        atomicAdd(&nh[etmp[e0 + i].y & (RWIDTH - 1)], 1);
    __syncthreads();
    if (t < RWIDTH) lo[t] = nh[t];
    __syncthreads();
    for (int off = 1; off < RWIDTH; off <<= 1) {
        int x = 0;
        if (t < RWIDTH && t >= off) x = lo[t - off];
        __syncthreads();
        if (t < RWIDTH) lo[t] += x;
        __syncthreads();
    }
    if (t < RWIDTH) {
        int ex = lo[t] - nh[t];               // exclusive
        lc[t] = ex;
        int node = b * RWIDTH + t;
        if (node < n_nodes) ptr[node] = e0 + ex;
    }
    __syncthreads();
    for (int i = t; i < cnt; i += 256) {
        int2 r = etmp[e0 + i];
        int p = atomicAdd(&lc[r.y & (RWIDTH - 1)], 1);
        ebin[e0 + p] = make_int2(r.x, r.y >> RSHIFT);
    }
}

// H16[n][j] = (f16) sum_k X[n][k]*W[j][k]; LDS-free MFMA, 4 waves x 16 rows
__global__ __launch_bounds__(256) void gemm_mfma_kernel(const float* __restrict__ X,
                                                        const f16* __restrict__ wf,
                                                        f16* __restrict__ H,
                                                        int n_nodes) {
    const int lane = threadIdx.x & 63;
    const int w = threadIdx.x >> 6;
    const int m0 = blockIdx.x * 64 + w * 16;
    int arow = m0 + (lane & 15);
    if (arow >= n_nodes) arow = n_nodes - 1;
    const float* xp = X + (size_t)arow * F_IN + ((lane >> 4) << 3);
    const f16x8* wfv = reinterpret_cast<const f16x8*>(wf);

    f32x4 acc0 = {}, acc1 = {}, acc2 = {}, acc3 = {};
    for (int s = 0; s < 16; ++s) {
        const f16x8* bp = wfv + (size_t)(s * 4) * 64 + lane;
        f16x8 b0 = bp[0];
        f16x8 b1 = bp[64];
        f16x8 b2 = bp[128];
        f16x8 b3 = bp[192];
        float4 xa = *reinterpret_cast<const float4*>(xp + s * 32);
        float4 xb = *reinterpret_cast<const float4*>(xp + s * 32 + 4);
        f16x8 a;
        a[0] = (f16)xa.x; a[1] = (f16)xa.y; a[2] = (f16)xa.z; a[3] = (f16)xa.w;
        a[4] = (f16)xb.x; a[5] = (f16)xb.y; a[6] = (f16)xb.z; a[7] = (f16)xb.w;
        acc0 = __builtin_amdgcn_mfma_f32_16x16x32_f16(a, b0, acc0, 0, 0, 0);
        acc1 = __builtin_amdgcn_mfma_f32_16x16x32_f16(a, b1, acc1, 0, 0, 0);
        acc2 = __builtin_amdgcn_mfma_f32_16x16x32_f16(a, b2, acc2, 0, 0, 0);
        acc3 = __builtin_amdgcn_mfma_f32_16x16x32_f16(a, b3, acc3, 0, 0, 0);
    }

    const int colj = lane & 15;
#pragma unroll
    for (int j = 0; j < 4; ++j) {
        int r = m0 + ((lane >> 4) << 2) + j;
        if (r < n_nodes) {
            f16* hp = H + (size_t)r * HDIM + colj;
            hp[0]  = (f16)acc0[j];
            hp[16] = (f16)acc1[j];
            hp[32] = (f16)acc2[j];
            hp[48] = (f16)acc3[j];
        }
    }
}

// per-node wave gather + bias + PReLU + wsum-dot -> z[n]; 4-deep load pipeline
__global__ __launch_bounds__(256) void agg_finalize_kernel(const int* __restrict__ ptr,
                                                           const int2* __restrict__ ebin,
                                                           const f16* __restrict__ h,
                                                           const float* __restrict__ gbias,
                                                           const float* __restrict__ wsum,
                                                           const float* __restrict__ prelu_a,
                                                           float* __restrict__ z,
                                                           int n_nodes) {
    const int lane = threadIdx.x & 63;
    const int wv = threadIdx.x >> 6;
    const int n = blockIdx.x * 4 + wv;
    if (n >= n_nodes) return;
    const int p0 = __builtin_amdgcn_readfirstlane(ptr[n]);
    const int p1 = __builtin_amdgcn_readfirstlane(ptr[n + 1]);
    float acc = 0.f;
    int i = p0;
    for (; i + 3 < p1; i += 4) {
        int2 e0 = ebin[i];
        int2 e1 = ebin[i + 1];
        int2 e2 = ebin[i + 2];
        int2 e3 = ebin[i + 3];
        float h0 = (float)h[(size_t)e0.y * HDIM + lane];
        float h1 = (float)h[(size_t)e1.y * HDIM + lane];
        float h2 = (float)h[(size_t)e2.y * HDIM + lane];
        float h3 = (float)h[(size_t)e3.y * HDIM + lane];
        acc = fmaf(__int_as_float(e0.x), h0, acc);
        acc = fmaf(__int_as_float(e1.x), h1, acc);
        acc = fmaf(__int_as_float(e2.x), h2, acc);
        acc = fmaf(__int_as_float(e3.x), h3, acc);
    }
    for (; i < p1; ++i) {
        int2 e0 = ebin[i];
        acc = fmaf(__int_as_float(e0.x), (float)h[(size_t)e0.y * HDIM + lane], acc);
    }
    float v = acc + gbias[lane];
    const float a = prelu_a[0];
    v = (v >= 0.f) ? v : a * v;
    float p = v * wsum[lane];
#pragma unroll
    for (int m = 32; m >= 1; m >>= 1) p += __shfl_xor(p, m, 64);
    if (lane == 0) z[n] = p + wsum[HDIM];
}

extern "C" void kernel_launch(void* const* d_in, const int* in_sizes, int n_in,
                              void* d_out, int out_size, void* d_ws, size_t ws_size,
                              hipStream_t stream) {
    const float* x1    = (const float*)d_in[0];
    const float* x2    = (const float*)d_in[1];
    const int*   erow  = (const int*)d_in[2];
    const int*   ecol  = (const int*)d_in[3];
    const float* ew    = (const float*)d_in[4];
    const float* fcw   = (const float*)d_in[5];
    const float* gbias = (const float*)d_in[6];
    const float* pa    = (const float*)d_in[7];
    const float* linw  = (const float*)d_in[8];
    const float* linb  = (const float*)d_in[9];
    float* out = (float*)d_out;

    const int n_nodes = in_sizes[0] / F_IN;   // 100000
    const int n_edges = in_sizes[2];          // 1600000
    const int NB = (n_nodes + RWIDTH - 1) >> RSHIFT;   // 782

    // workspace layout
    f16*   h16  = (f16*)d_ws;                           // n_nodes*64 f16
    f16*   wf   = h16 + (size_t)n_nodes * HDIM;         // 64*512 f16
    int2*  etmp = (int2*)(wf + 64 * F_IN);              // n_edges int2
    int2*  ebin = etmp + n_edges;                       // n_edges int2
    int*   bh   = (int*)(ebin + n_edges);               // MAXNB
    int*   boff = bh + MAXNB;                           // MAXNB+1
    int*   gcur = boff + MAXNB + 1;                     // MAXNB
    int*   ptr  = gcur + MAXNB;                         // n_nodes+1
    float* wsum = (float*)(ptr + n_nodes + 1);          // 65 f32

    prep_kernel<<<1, 64, 0, stream>>>(linw, linb, wsum);
    prep_w16_kernel<<<16, 256, 0, stream>>>(fcw, wf);

    zero_int_kernel<<<(NB + 255) / 256, 256, 0, stream>>>(bh, NB);
    bhist_kernel<<<256, 256, 0, stream>>>(erow, bh, n_edges, NB);
    bscan_kernel<<<1, 1024, 0, stream>>>(bh, boff, gcur, ptr, NB, n_nodes, n_edges);
    part_kernel<<<(n_edges + CHUNK - 1) / CHUNK, 256, 0, stream>>>(erow, ecol, ew, gcur,
                                                                   etmp, n_edges, NB);
    bsort_kernel<<<NB, 256, 0, stream>>>(boff, etmp, ebin, ptr, n_nodes);

    const int gemm_grid = (n_nodes + 63) / 64;
    const int fin_grid  = (n_nodes + 3) / 4;
    const float* xs[2] = {x1, x2};
    for (int s = 0; s < 2; ++s) {
        gemm_mfma_kernel<<<gemm_grid, 256, 0, stream>>>(xs[s], wf, h16, n_nodes);
        agg_finalize_kernel<<<fin_grid, 256, 0, stream>>>(ptr, ebin, h16, gbias, wsum, pa,
                                                          out + (size_t)s * n_nodes, n_nodes);
    }
}

// Round 6
// 249.712 us; speedup vs baseline: 6.1749x; 1.1965x over previous
//
#include <hip/hip_runtime.h>

#define F_IN 512
#define HDIM 64
#define RSHIFT 7
#define RWIDTH 128
#define MAXNB 1024
#define CHUNK 4096

typedef _Float16 f16;
typedef _Float16 f16x2 __attribute__((ext_vector_type(2)));
typedef _Float16 f16x8 __attribute__((ext_vector_type(8)));
typedef float f32x4 __attribute__((ext_vector_type(4)));

// wsum[k] = sum_j linW[j][k]; wsum[64] = sum_j linB[j]
__global__ void prep_kernel(const float* __restrict__ linW,
                            const float* __restrict__ linB,
                            float* __restrict__ wsum) {
    int k = threadIdx.x;
    float s = 0.f;
    for (int j = 0; j < HDIM; ++j) s += linW[j * HDIM + k];
    wsum[k] = s;
    if (k == 0) {
        float b = 0.f;
        for (int j = 0; j < HDIM; ++j) b += linB[j];
        wsum[HDIM] = b;
    }
}

// fc_weight as f16 in B-fragment order:
// wf[((s*4 + c)*64 + lane)*8 + j] = W[c*16 + (lane&15)][s*32 + (lane>>4)*8 + j]
__global__ __launch_bounds__(256) void prep_w16_kernel(const float* __restrict__ W,
                                                       f16* __restrict__ wf) {
    int t = blockIdx.x * 256 + threadIdx.x;   // 0..4095
    int s = t >> 8;
    int c = (t >> 6) & 3;
    int l = t & 63;
    int row = c * 16 + (l & 15);
    int kb = s * 32 + ((l >> 4) << 3);
#pragma unroll
    for (int j = 0; j < 8; ++j)
        wf[(size_t)t * 8 + j] = (f16)W[row * F_IN + kb + j];
}

__global__ void zero_int_kernel(int* __restrict__ p, int n) {
    int i = blockIdx.x * blockDim.x + threadIdx.x;
    if (i < n) p[i] = 0;
}

// bucket histogram, LDS-pre-aggregated
__global__ __launch_bounds__(256) void bhist_kernel(const int* __restrict__ row,
                                                    int* __restrict__ bh,
                                                    int n_edges, int NB) {
    __shared__ int lh[MAXNB];
    for (int i = threadIdx.x; i < NB; i += 256) lh[i] = 0;
    __syncthreads();
    for (int e = blockIdx.x * 256 + threadIdx.x; e < n_edges; e += gridDim.x * 256)
        atomicAdd(&lh[row[e] >> RSHIFT], 1);
    __syncthreads();
    for (int i = threadIdx.x; i < NB; i += 256)
        if (lh[i]) atomicAdd(&bh[i], lh[i]);
}

// one block: exclusive scan of bh -> boff; init gcur; ptr[n_nodes] = n_edges
__global__ __launch_bounds__(1024) void bscan_kernel(const int* __restrict__ bh,
                                                     int* __restrict__ boff,
                                                     int* __restrict__ gcur,
                                                     int* __restrict__ ptr,
                                                     int NB, int n_nodes, int n_edges) {
    __shared__ int s[1024];
    const int t = threadIdx.x;
    int v = (t < NB) ? bh[t] : 0;
    s[t] = v;
    __syncthreads();
#pragma unroll
    for (int off = 1; off < 1024; off <<= 1) {
        int x = (t >= off) ? s[t - off] : 0;
        __syncthreads();
        s[t] += x;
        __syncthreads();
    }
    if (t < NB) {
        int o = s[t] - v;
        boff[t] = o;
        gcur[t] = o;
    }
    if (t == NB) boff[NB] = n_edges;
    if (t == 0) ptr[n_nodes] = n_edges;
}

// partition: per-block counting sort by bucket in LDS, append runs to global regions.
// record: (w_bits, col<<7 | row&127)
__global__ __launch_bounds__(256) void part_kernel(const int* __restrict__ row,
                                                   const int* __restrict__ col,
                                                   const float* __restrict__ w,
                                                   int* __restrict__ gcur,
                                                   int2* __restrict__ etmp,
                                                   int n_edges, int NB) {
    __shared__ int2 stg[CHUNK];             // 32 KB
    __shared__ unsigned short sbin[CHUNK];  // 8 KB
    __shared__ int lh[MAXNB];
    __shared__ int lofs[MAXNB];
    __shared__ int psum[256];
    const int t = threadIdx.x;
    const int base = blockIdx.x * CHUNK;
    const int cnt = min(CHUNK, n_edges - base);

    for (int i = t; i < NB; i += 256) lh[i] = 0;
    __syncthreads();
    for (int i = t; i < cnt; i += 256)
        atomicAdd(&lh[row[base + i] >> RSHIFT], 1);
    __syncthreads();
    int loc[4];
    int s0 = 0;
#pragma unroll
    for (int j = 0; j < 4; ++j) {
        int b = t * 4 + j;
        int c = (b < NB) ? lh[b] : 0;
        loc[j] = s0;
        s0 += c;
    }
    psum[t] = s0;
    __syncthreads();
#pragma unroll
    for (int off = 1; off < 256; off <<= 1) {
        int x = (t >= off) ? psum[t - off] : 0;
        __syncthreads();
        psum[t] += x;
        __syncthreads();
    }
    int pbase = psum[t] - s0;
#pragma unroll
    for (int j = 0; j < 4; ++j) {
        int b = t * 4 + j;
        if (b < NB) lofs[b] = pbase + loc[j];
    }
    __syncthreads();
    for (int i = t; i < cnt; i += 256) {
        int r = row[base + i];
        int b = r >> RSHIFT;
        int p = atomicAdd(&lofs[b], 1);
        stg[p] = make_int2(__float_as_int(w[base + i]),
                           (col[base + i] << RSHIFT) | (r & (RWIDTH - 1)));
        sbin[p] = (unsigned short)b;
    }
    __syncthreads();
    for (int b = t; b < NB; b += 256) {
        int c = lh[b];
        if (c) {
            int lstart = lofs[b] - c;
            int gb = atomicAdd(&gcur[b], c);
            lh[b] = gb - lstart;
        }
    }
    __syncthreads();
    for (int p = t; p < cnt; p += 256) {
        int b = sbin[p];
        etmp[lh[b] + p] = stg[p];
    }
}

// per-bucket counting sort -> full CSR order; write ptr. record out: (w_bits, col)
__global__ __launch_bounds__(256) void bsort_kernel(const int* __restrict__ boff,
                                                    const int2* __restrict__ etmp,
                                                    int2* __restrict__ ebin,
                                                    int* __restrict__ ptr,
                                                    int n_nodes) {
    __shared__ int nh[RWIDTH], lo[RWIDTH], lc[RWIDTH];
    const int b = blockIdx.x;
    const int t = threadIdx.x;
    const int e0 = boff[b], e1 = boff[b + 1];
    const int cnt = e1 - e0;
    if (t < RWIDTH) nh[t] = 0;
    __syncthreads();
    for (int i = t; i < cnt; i += 256)
        atomicAdd(&nh[etmp[e0 + i].y & (RWIDTH - 1)], 1);
    __syncthreads();
    if (t < RWIDTH) lo[t] = nh[t];
    __syncthreads();
    for (int off = 1; off < RWIDTH; off <<= 1) {
        int x = 0;
        if (t < RWIDTH && t >= off) x = lo[t - off];
        __syncthreads();
        if (t < RWIDTH) lo[t] += x;
        __syncthreads();
    }
    if (t < RWIDTH) {
        int ex = lo[t] - nh[t];               // exclusive
        lc[t] = ex;
        int node = b * RWIDTH + t;
        if (node < n_nodes) ptr[node] = e0 + ex;
    }
    __syncthreads();
    for (int i = t; i < cnt; i += 256) {
        int2 r = etmp[e0 + i];
        int p = atomicAdd(&lc[r.y & (RWIDTH - 1)], 1);
        ebin[e0 + p] = make_int2(r.x, r.y >> RSHIFT);
    }
}

// Both GCN fc passes: blockIdx.y = pass. H layout: [node][j*2 + pass] f16 (256B rows)
__global__ __launch_bounds__(256) void gemm_both_kernel(const float* __restrict__ X1,
                                                        const float* __restrict__ X2,
                                                        const f16* __restrict__ wf,
                                                        f16* __restrict__ H,
                                                        int n_nodes) {
    const float* X = blockIdx.y ? X2 : X1;
    const int pass = blockIdx.y;
    const int lane = threadIdx.x & 63;
    const int w = threadIdx.x >> 6;
    const int m0 = blockIdx.x * 64 + w * 16;
    int arow = m0 + (lane & 15);
    if (arow >= n_nodes) arow = n_nodes - 1;
    const float* xp = X + (size_t)arow * F_IN + ((lane >> 4) << 3);
    const f16x8* wfv = reinterpret_cast<const f16x8*>(wf);

    f32x4 acc0 = {}, acc1 = {}, acc2 = {}, acc3 = {};
    for (int s = 0; s < 16; ++s) {
        const f16x8* bp = wfv + (size_t)(s * 4) * 64 + lane;
        f16x8 b0 = bp[0];
        f16x8 b1 = bp[64];
        f16x8 b2 = bp[128];
        f16x8 b3 = bp[192];
        float4 xa = *reinterpret_cast<const float4*>(xp + s * 32);
        float4 xb = *reinterpret_cast<const float4*>(xp + s * 32 + 4);
        f16x8 a;
        a[0] = (f16)xa.x; a[1] = (f16)xa.y; a[2] = (f16)xa.z; a[3] = (f16)xa.w;
        a[4] = (f16)xb.x; a[5] = (f16)xb.y; a[6] = (f16)xb.z; a[7] = (f16)xb.w;
        acc0 = __builtin_amdgcn_mfma_f32_16x16x32_f16(a, b0, acc0, 0, 0, 0);
        acc1 = __builtin_amdgcn_mfma_f32_16x16x32_f16(a, b1, acc1, 0, 0, 0);
        acc2 = __builtin_amdgcn_mfma_f32_16x16x32_f16(a, b2, acc2, 0, 0, 0);
        acc3 = __builtin_amdgcn_mfma_f32_16x16x32_f16(a, b3, acc3, 0, 0, 0);
    }

    const int colj = lane & 15;
#pragma unroll
    for (int j = 0; j < 4; ++j) {
        int r = m0 + ((lane >> 4) << 2) + j;
        if (r < n_nodes) {
            f16* hp = H + (size_t)r * 2 * HDIM + colj * 2 + pass;
            hp[0]  = (f16)acc0[j];
            hp[32] = (f16)acc1[j];
            hp[64] = (f16)acc2[j];
            hp[96] = (f16)acc3[j];
        }
    }
}

// per-node wave gather, BOTH passes at once; 4-deep load pipeline.
// h layout [node][j*2+pass]: lane loads f16x2 = both passes of feature `lane`.
__global__ __launch_bounds__(256) void agg_both_kernel(const int* __restrict__ ptr,
                                                       const int2* __restrict__ ebin,
                                                       const f16* __restrict__ h,
                                                       const float* __restrict__ gbias,
                                                       const float* __restrict__ wsum,
                                                       const float* __restrict__ prelu_a,
                                                       float* __restrict__ z,
                                                       int n_nodes) {
    const int lane = threadIdx.x & 63;
    const int wv = threadIdx.x >> 6;
    const int n = blockIdx.x * 4 + wv;
    if (n >= n_nodes) return;
    const f16x2* hv = reinterpret_cast<const f16x2*>(h) + lane;
    const int p0 = __builtin_amdgcn_readfirstlane(ptr[n]);
    const int p1 = __builtin_amdgcn_readfirstlane(ptr[n + 1]);
    float acc1 = 0.f, acc2 = 0.f;
    int i = p0;
    for (; i + 3 < p1; i += 4) {
        int2 e0 = ebin[i];
        int2 e1 = ebin[i + 1];
        int2 e2 = ebin[i + 2];
        int2 e3 = ebin[i + 3];
        f16x2 h0 = hv[(size_t)e0.y * HDIM];
        f16x2 h1 = hv[(size_t)e1.y * HDIM];
        f16x2 h2 = hv[(size_t)e2.y * HDIM];
        f16x2 h3 = hv[(size_t)e3.y * HDIM];
        float w0 = __int_as_float(e0.x), w1 = __int_as_float(e1.x);
        float w2 = __int_as_float(e2.x), w3 = __int_as_float(e3.x);
        acc1 = fmaf(w0, (float)h0[0], acc1);
        acc2 = fmaf(w0, (float)h0[1], acc2);
        acc1 = fmaf(w1, (float)h1[0], acc1);
        acc2 = fmaf(w1, (float)h1[1], acc2);
        acc1 = fmaf(w2, (float)h2[0], acc1);
        acc2 = fmaf(w2, (float)h2[1], acc2);
        acc1 = fmaf(w3, (float)h3[0], acc1);
        acc2 = fmaf(w3, (float)h3[1], acc2);
    }
    for (; i < p1; ++i) {
        int2 e0 = ebin[i];
        f16x2 h0 = hv[(size_t)e0.y * HDIM];
        float w0 = __int_as_float(e0.x);
        acc1 = fmaf(w0, (float)h0[0], acc1);
        acc2 = fmaf(w0, (float)h0[1], acc2);
    }
    const float a = prelu_a[0];
    const float gb = gbias[lane];
    const float wl = wsum[lane];
    float v1 = acc1 + gb;
    float v2 = acc2 + gb;
    v1 = (v1 >= 0.f) ? v1 : a * v1;
    v2 = (v2 >= 0.f) ? v2 : a * v2;
    float q1 = v1 * wl;
    float q2 = v2 * wl;
#pragma unroll
    for (int m = 32; m >= 1; m >>= 1) {
        q1 += __shfl_xor(q1, m, 64);
        q2 += __shfl_xor(q2, m, 64);
    }
    if (lane == 0) {
        z[n] = q1 + wsum[HDIM];
        z[n + n_nodes] = q2 + wsum[HDIM];
    }
}

extern "C" void kernel_launch(void* const* d_in, const int* in_sizes, int n_in,
                              void* d_out, int out_size, void* d_ws, size_t ws_size,
                              hipStream_t stream) {
    const float* x1    = (const float*)d_in[0];
    const float* x2    = (const float*)d_in[1];
    const int*   erow  = (const int*)d_in[2];
    const int*   ecol  = (const int*)d_in[3];
    const float* ew    = (const float*)d_in[4];
    const float* fcw   = (const float*)d_in[5];
    const float* gbias = (const float*)d_in[6];
    const float* pa    = (const float*)d_in[7];
    const float* linw  = (const float*)d_in[8];
    const float* linb  = (const float*)d_in[9];
    float* out = (float*)d_out;

    const int n_nodes = in_sizes[0] / F_IN;   // 100000
    const int n_edges = in_sizes[2];          // 1600000
    const int NB = (n_nodes + RWIDTH - 1) >> RSHIFT;   // 782

    // workspace layout
    f16*   h16  = (f16*)d_ws;                           // n_nodes*128 f16 (both passes)
    f16*   wf   = h16 + (size_t)n_nodes * 2 * HDIM;     // 64*512 f16
    int2*  etmp = (int2*)(wf + 64 * F_IN);              // n_edges int2
    int2*  ebin = etmp + n_edges;                       // n_edges int2
    int*   bh   = (int*)(ebin + n_edges);               // MAXNB
    int*   boff = bh + MAXNB;                           // MAXNB+1
    int*   gcur = boff + MAXNB + 1;                     // MAXNB
    int*   ptr  = gcur + MAXNB;                         // n_nodes+1
    float* wsum = (float*)(ptr + n_nodes + 1);          // 65 f32

    prep_kernel<<<1, 64, 0, stream>>>(linw, linb, wsum);
    prep_w16_kernel<<<16, 256, 0, stream>>>(fcw, wf);

    zero_int_kernel<<<(NB + 255) / 256, 256, 0, stream>>>(bh, NB);
    bhist_kernel<<<256, 256, 0, stream>>>(erow, bh, n_edges, NB);
    bscan_kernel<<<1, 1024, 0, stream>>>(bh, boff, gcur, ptr, NB, n_nodes, n_edges);
    part_kernel<<<(n_edges + CHUNK - 1) / CHUNK, 256, 0, stream>>>(erow, ecol, ew, gcur,
                                                                   etmp, n_edges, NB);
    bsort_kernel<<<NB, 256, 0, stream>>>(boff, etmp, ebin, ptr, n_nodes);

    const int gemm_grid = (n_nodes + 63) / 64;
    const int fin_grid  = (n_nodes + 3) / 4;
    gemm_both_kernel<<<dim3(gemm_grid, 2), 256, 0, stream>>>(x1, x2, wf, h16, n_nodes);
    agg_both_kernel<<<fin_grid, 256, 0, stream>>>(ptr, ebin, h16, gbias, wsum, pa,
                                                  out, n_nodes);
}

// Round 7
// 229.754 us; speedup vs baseline: 6.7113x; 1.0869x over previous
//
#include <hip/hip_runtime.h>

#define F_IN 512
#define HDIM 64
#define RSHIFT 7
#define RWIDTH 128
#define MAXNB 1024
#define CHUNK 4096
#define BKF 128   // f32 per K-chunk in gemm staging

typedef _Float16 f16;
typedef _Float16 f16x2 __attribute__((ext_vector_type(2)));
typedef _Float16 f16x8 __attribute__((ext_vector_type(8)));
typedef float f32x4 __attribute__((ext_vector_type(4)));

#define GLOAD_LDS16(src, dst)                                                        \
    __builtin_amdgcn_global_load_lds((const __attribute__((address_space(1))) void*)(src), \
                                     (__attribute__((address_space(3))) void*)(dst), 16, 0, 0)

// wsum[k] = sum_j linW[j][k]; wsum[64] = sum_j linB[j]
__global__ void prep_kernel(const float* __restrict__ linW,
                            const float* __restrict__ linB,
                            float* __restrict__ wsum) {
    int k = threadIdx.x;
    float s = 0.f;
    for (int j = 0; j < HDIM; ++j) s += linW[j * HDIM + k];
    wsum[k] = s;
    if (k == 0) {
        float b = 0.f;
        for (int j = 0; j < HDIM; ++j) b += linB[j];
        wsum[HDIM] = b;
    }
}

// fc_weight as f16 in B-fragment order:
// wf[((s*4 + c)*64 + lane)*8 + j] = W[c*16 + (lane&15)][s*32 + (lane>>4)*8 + j]
__global__ __launch_bounds__(256) void prep_w16_kernel(const float* __restrict__ W,
                                                       f16* __restrict__ wf) {
    int t = blockIdx.x * 256 + threadIdx.x;   // 0..4095
    int s = t >> 8;
    int c = (t >> 6) & 3;
    int l = t & 63;
    int row = c * 16 + (l & 15);
    int kb = s * 32 + ((l >> 4) << 3);
#pragma unroll
    for (int j = 0; j < 8; ++j)
        wf[(size_t)t * 8 + j] = (f16)W[row * F_IN + kb + j];
}

__global__ void zero_int_kernel(int* __restrict__ p, int n) {
    int i = blockIdx.x * blockDim.x + threadIdx.x;
    if (i < n) p[i] = 0;
}

// bucket histogram, LDS-pre-aggregated
__global__ __launch_bounds__(256) void bhist_kernel(const int* __restrict__ row,
                                                    int* __restrict__ bh,
                                                    int n_edges, int NB) {
    __shared__ int lh[MAXNB];
    for (int i = threadIdx.x; i < NB; i += 256) lh[i] = 0;
    __syncthreads();
    for (int e = blockIdx.x * 256 + threadIdx.x; e < n_edges; e += gridDim.x * 256)
        atomicAdd(&lh[row[e] >> RSHIFT], 1);
    __syncthreads();
    for (int i = threadIdx.x; i < NB; i += 256)
        if (lh[i]) atomicAdd(&bh[i], lh[i]);
}

// one block: exclusive scan of bh -> boff; init gcur; ptr[n_nodes] = n_edges
__global__ __launch_bounds__(1024) void bscan_kernel(const int* __restrict__ bh,
                                                     int* __restrict__ boff,
                                                     int* __restrict__ gcur,
                                                     int* __restrict__ ptr,
                                                     int NB, int n_nodes, int n_edges) {
    __shared__ int s[1024];
    const int t = threadIdx.x;
    int v = (t < NB) ? bh[t] : 0;
    s[t] = v;
    __syncthreads();
#pragma unroll
    for (int off = 1; off < 1024; off <<= 1) {
        int x = (t >= off) ? s[t - off] : 0;
        __syncthreads();
        s[t] += x;
        __syncthreads();
    }
    if (t < NB) {
        int o = s[t] - v;
        boff[t] = o;
        gcur[t] = o;
    }
    if (t == NB) boff[NB] = n_edges;
    if (t == 0) ptr[n_nodes] = n_edges;
}

// partition: per-block counting sort by bucket in LDS, append runs to global regions.
// record: (w_bits, col<<7 | row&127)
__global__ __launch_bounds__(256) void part_kernel(const int* __restrict__ row,
                                                   const int* __restrict__ col,
                                                   const float* __restrict__ w,
                                                   int* __restrict__ gcur,
                                                   int2* __restrict__ etmp,
                                                   int n_edges, int NB) {
    __shared__ int2 stg[CHUNK];             // 32 KB
    __shared__ unsigned short sbin[CHUNK];  // 8 KB
    __shared__ int lh[MAXNB];
    __shared__ int lofs[MAXNB];
    __shared__ int psum[256];
    const int t = threadIdx.x;
    const int base = blockIdx.x * CHUNK;
    const int cnt = min(CHUNK, n_edges - base);

    for (int i = t; i < NB; i += 256) lh[i] = 0;
    __syncthreads();
    for (int i = t; i < cnt; i += 256)
        atomicAdd(&lh[row[base + i] >> RSHIFT], 1);
    __syncthreads();
    int loc[4];
    int s0 = 0;
#pragma unroll
    for (int j = 0; j < 4; ++j) {
        int b = t * 4 + j;
        int c = (b < NB) ? lh[b] : 0;
        loc[j] = s0;
        s0 += c;
    }
    psum[t] = s0;
    __syncthreads();
#pragma unroll
    for (int off = 1; off < 256; off <<= 1) {
        int x = (t >= off) ? psum[t - off] : 0;
        __syncthreads();
        psum[t] += x;
        __syncthreads();
    }
    int pbase = psum[t] - s0;
#pragma unroll
    for (int j = 0; j < 4; ++j) {
        int b = t * 4 + j;
        if (b < NB) lofs[b] = pbase + loc[j];
    }
    __syncthreads();
    for (int i = t; i < cnt; i += 256) {
        int r = row[base + i];
        int b = r >> RSHIFT;
        int p = atomicAdd(&lofs[b], 1);
        stg[p] = make_int2(__float_as_int(w[base + i]),
                           (col[base + i] << RSHIFT) | (r & (RWIDTH - 1)));
        sbin[p] = (unsigned short)b;
    }
    __syncthreads();
    for (int b = t; b < NB; b += 256) {
        int c = lh[b];
        if (c) {
            int lstart = lofs[b] - c;
            int gb = atomicAdd(&gcur[b], c);
            lh[b] = gb - lstart;
        }
    }
    __syncthreads();
    for (int p = t; p < cnt; p += 256) {
        int b = sbin[p];
        etmp[lh[b] + p] = stg[p];
    }
}

// per-bucket counting sort -> full CSR order; write ptr. record out: (w_bits, col)
__global__ __launch_bounds__(256) void bsort_kernel(const int* __restrict__ boff,
                                                    const int2* __restrict__ etmp,
                                                    int2* __restrict__ ebin,
                                                    int* __restrict__ ptr,
                                                    int n_nodes) {
    __shared__ int nh[RWIDTH], lo[RWIDTH], lc[RWIDTH];
    const int b = blockIdx.x;
    const int t = threadIdx.x;
    const int e0 = boff[b], e1 = boff[b + 1];
    const int cnt = e1 - e0;
    if (t < RWIDTH) nh[t] = 0;
    __syncthreads();
    for (int i = t; i < cnt; i += 256)
        atomicAdd(&nh[etmp[e0 + i].y & (RWIDTH - 1)], 1);
    __syncthreads();
    if (t < RWIDTH) lo[t] = nh[t];
    __syncthreads();
    for (int off = 1; off < RWIDTH; off <<= 1) {
        int x = 0;
        if (t < RWIDTH && t >= off) x = lo[t - off];
        __syncthreads();
        if (t < RWIDTH) lo[t] += x;
        __syncthreads();
    }
    if (t < RWIDTH) {
        int ex = lo[t] - nh[t];               // exclusive
        lc[t] = ex;
        int node = b * RWIDTH + t;
        if (node < n_nodes) ptr[node] = e0 + ex;
    }
    __syncthreads();
    for (int i = t; i < cnt; i += 256) {
        int2 r = etmp[e0 + i];
        int p = atomicAdd(&lc[r.y & (RWIDTH - 1)], 1);
        ebin[e0 + p] = make_int2(r.x, r.y >> RSHIFT);
    }
}

// Both GCN fc passes, LDS-staged via global_load_lds.
// LDS tile: 64 rows x BKF f32 (32 KB), XOR-swizzled: LDS[row][sub] = X[row][sub ^ ((row&7)<<4)]
// (swizzle applied on global SOURCE addr; ds_read applies same XOR -> bank-uniform)
// H layout: [node][j*2 + pass] f16 (256B rows)
__global__ __launch_bounds__(256) void gemm_both_kernel(const float* __restrict__ X1,
                                                        const float* __restrict__ X2,
                                                        const f16* __restrict__ wf,
                                                        f16* __restrict__ H,
                                                        int n_nodes) {
    __shared__ float xs[64 * BKF];   // 32 KB
    const float* X = blockIdx.y ? X2 : X1;
    const int pass = blockIdx.y;
    const int t = threadIdx.x;
    const int lane = t & 63;
    const int w = t >> 6;
    const int m0 = blockIdx.x * 64;
    const f16x8* wfv = reinterpret_cast<const f16x8*>(wf);

    // staging geometry (512 B per LDS row): off = p*4096 + w*1024 + lane*16
    const int srow_base = w * 2 + (lane >> 5);         // + p*8
    const int ssub = (lane & 31) << 4;                 // byte within row
    char* sdst_base = (char*)xs + w * 1024;            // wave-uniform, + p*4096

    // compute geometry
    const int rl = w * 16 + (lane & 15);               // local row this lane computes
    const int g = lane >> 4;
    const int sw = (rl & 7) << 4;
    const char* xrow = (const char*)xs + rl * 512;

    f32x4 acc0 = {}, acc1 = {}, acc2 = {}, acc3 = {};

    for (int c = 0; c < 4; ++c) {
        const int k0 = c * BKF;
        // stage chunk c (8 x 16B async per thread)
#pragma unroll
        for (int p = 0; p < 8; ++p) {
            int row = p * 8 + srow_base;
            int gm = m0 + row;
            if (gm >= n_nodes) gm = n_nodes - 1;
            const char* src = (const char*)(X + (size_t)gm * F_IN + k0) +
                              (ssub ^ ((row & 7) << 4));
            GLOAD_LDS16(src, sdst_base + p * 4096);
        }
        __syncthreads();   // drains vmcnt -> staged data visible
#pragma unroll
        for (int ks = 0; ks < 4; ++ks) {
            const int s = c * 4 + ks;
            const f16x8* bp = wfv + (size_t)(s * 4) * 64 + lane;
            f16x8 b0 = bp[0];
            f16x8 b1 = bp[64];
            f16x8 b2 = bp[128];
            f16x8 b3 = bp[192];
            const int c0 = ks * 128 + g * 32;
            float4 xa = *reinterpret_cast<const float4*>(xrow + (c0 ^ sw));
            float4 xb = *reinterpret_cast<const float4*>(xrow + ((c0 + 16) ^ sw));
            f16x8 a;
            a[0] = (f16)xa.x; a[1] = (f16)xa.y; a[2] = (f16)xa.z; a[3] = (f16)xa.w;
            a[4] = (f16)xb.x; a[5] = (f16)xb.y; a[6] = (f16)xb.z; a[7] = (f16)xb.w;
            acc0 = __builtin_amdgcn_mfma_f32_16x16x32_f16(a, b0, acc0, 0, 0, 0);
            acc1 = __builtin_amdgcn_mfma_f32_16x16x32_f16(a, b1, acc1, 0, 0, 0);
            acc2 = __builtin_amdgcn_mfma_f32_16x16x32_f16(a, b2, acc2, 0, 0, 0);
            acc3 = __builtin_amdgcn_mfma_f32_16x16x32_f16(a, b3, acc3, 0, 0, 0);
        }
        __syncthreads();   // WAR: buffer reuse next chunk
    }

    const int m0w = m0 + w * 16;
    const int colj = lane & 15;
#pragma unroll
    for (int j = 0; j < 4; ++j) {
        int r = m0w + ((lane >> 4) << 2) + j;
        if (r < n_nodes) {
            f16* hp = H + (size_t)r * 2 * HDIM + colj * 2 + pass;
            hp[0]  = (f16)acc0[j];
            hp[32] = (f16)acc1[j];
            hp[64] = (f16)acc2[j];
            hp[96] = (f16)acc3[j];
        }
    }
}

// per-node wave gather, BOTH passes at once; 4-deep load pipeline.
// h layout [node][j*2+pass]: lane loads f16x2 = both passes of feature `lane`.
__global__ __launch_bounds__(256) void agg_both_kernel(const int* __restrict__ ptr,
                                                       const int2* __restrict__ ebin,
                                                       const f16* __restrict__ h,
                                                       const float* __restrict__ gbias,
                                                       const float* __restrict__ wsum,
                                                       const float* __restrict__ prelu_a,
                                                       float* __restrict__ z,
                                                       int n_nodes) {
    const int lane = threadIdx.x & 63;
    const int wv = threadIdx.x >> 6;
    const int n = blockIdx.x * 4 + wv;
    if (n >= n_nodes) return;
    const f16x2* hv = reinterpret_cast<const f16x2*>(h) + lane;
    const int p0 = __builtin_amdgcn_readfirstlane(ptr[n]);
    const int p1 = __builtin_amdgcn_readfirstlane(ptr[n + 1]);
    float acc1 = 0.f, acc2 = 0.f;
    int i = p0;
    for (; i + 3 < p1; i += 4) {
        int2 e0 = ebin[i];
        int2 e1 = ebin[i + 1];
        int2 e2 = ebin[i + 2];
        int2 e3 = ebin[i + 3];
        f16x2 h0 = hv[(size_t)e0.y * HDIM];
        f16x2 h1 = hv[(size_t)e1.y * HDIM];
        f16x2 h2 = hv[(size_t)e2.y * HDIM];
        f16x2 h3 = hv[(size_t)e3.y * HDIM];
        float w0 = __int_as_float(e0.x), w1 = __int_as_float(e1.x);
        float w2 = __int_as_float(e2.x), w3 = __int_as_float(e3.x);
        acc1 = fmaf(w0, (float)h0[0], acc1);
        acc2 = fmaf(w0, (float)h0[1], acc2);
        acc1 = fmaf(w1, (float)h1[0], acc1);
        acc2 = fmaf(w1, (float)h1[1], acc2);
        acc1 = fmaf(w2, (float)h2[0], acc1);
        acc2 = fmaf(w2, (float)h2[1], acc2);
        acc1 = fmaf(w3, (float)h3[0], acc1);
        acc2 = fmaf(w3, (float)h3[1], acc2);
    }
    for (; i < p1; ++i) {
        int2 e0 = ebin[i];
        f16x2 h0 = hv[(size_t)e0.y * HDIM];
        float w0 = __int_as_float(e0.x);
        acc1 = fmaf(w0, (float)h0[0], acc1);
        acc2 = fmaf(w0, (float)h0[1], acc2);
    }
    const float a = prelu_a[0];
    const float gb = gbias[lane];
    const float wl = wsum[lane];
    float v1 = acc1 + gb;
    float v2 = acc2 + gb;
    v1 = (v1 >= 0.f) ? v1 : a * v1;
    v2 = (v2 >= 0.f) ? v2 : a * v2;
    float q1 = v1 * wl;
    float q2 = v2 * wl;
#pragma unroll
    for (int m = 32; m >= 1; m >>= 1) {
        q1 += __shfl_xor(q1, m, 64);
        q2 += __shfl_xor(q2, m, 64);
    }
    if (lane == 0) {
        z[n] = q1 + wsum[HDIM];
        z[n + n_nodes] = q2 + wsum[HDIM];
    }
}

extern "C" void kernel_launch(void* const* d_in, const int* in_sizes, int n_in,
                              void* d_out, int out_size, void* d_ws, size_t ws_size,
                              hipStream_t stream) {
    const float* x1    = (const float*)d_in[0];
    const float* x2    = (const float*)d_in[1];
    const int*   erow  = (const int*)d_in[2];
    const int*   ecol  = (const int*)d_in[3];
    const float* ew    = (const float*)d_in[4];
    const float* fcw   = (const float*)d_in[5];
    const float* gbias = (const float*)d_in[6];
    const float* pa    = (const float*)d_in[7];
    const float* linw  = (const float*)d_in[8];
    const float* linb  = (const float*)d_in[9];
    float* out = (float*)d_out;

    const int n_nodes = in_sizes[0] / F_IN;   // 100000
    const int n_edges = in_sizes[2];          // 1600000
    const int NB = (n_nodes + RWIDTH - 1) >> RSHIFT;   // 782

    // workspace layout
    f16*   h16  = (f16*)d_ws;                           // n_nodes*128 f16 (both passes)
    f16*   wf   = h16 + (size_t)n_nodes * 2 * HDIM;     // 64*512 f16
    int2*  etmp = (int2*)(wf + 64 * F_IN);              // n_edges int2
    int2*  ebin = etmp + n_edges;                       // n_edges int2
    int*   bh   = (int*)(ebin + n_edges);               // MAXNB
    int*   boff = bh + MAXNB;                           // MAXNB+1
    int*   gcur = boff + MAXNB + 1;                     // MAXNB
    int*   ptr  = gcur + MAXNB;                         // n_nodes+1
    float* wsum = (float*)(ptr + n_nodes + 1);          // 65 f32

    prep_kernel<<<1, 64, 0, stream>>>(linw, linb, wsum);
    prep_w16_kernel<<<16, 256, 0, stream>>>(fcw, wf);

    zero_int_kernel<<<(NB + 255) / 256, 256, 0, stream>>>(bh, NB);
    bhist_kernel<<<256, 256, 0, stream>>>(erow, bh, n_edges, NB);
    bscan_kernel<<<1, 1024, 0, stream>>>(bh, boff, gcur, ptr, NB, n_nodes, n_edges);
    part_kernel<<<(n_edges + CHUNK - 1) / CHUNK, 256, 0, stream>>>(erow, ecol, ew, gcur,
                                                                   etmp, n_edges, NB);
    bsort_kernel<<<NB, 256, 0, stream>>>(boff, etmp, ebin, ptr, n_nodes);

    const int gemm_grid = (n_nodes + 63) / 64;
    const int fin_grid  = (n_nodes + 3) / 4;
    gemm_both_kernel<<<dim3(gemm_grid, 2), 256, 0, stream>>>(x1, x2, wf, h16, n_nodes);
    agg_both_kernel<<<fin_grid, 256, 0, stream>>>(ptr, ebin, h16, gbias, wsum, pa,
                                                  out, n_nodes);
}